// Round 1
// baseline (990.897 us; speedup 1.0000x reference)
//
#include <hip/hip_runtime.h>
#include <hip/hip_bf16.h>

#define D_DIM 512
#define E_DIM 64
#define JT    32   // j-chunk per block

// Kernel A: q = t @ Wq^T, k = t @ Wk^T   (per (b,n) row)
// grid = B*N blocks, 64 threads (= 1 wave), thread e computes q[b,n,e], k[b,n,e]
__global__ __launch_bounds__(64) void qk_proj_kernel(
    const float* __restrict__ t,    // (B*N, 512)
    const float* __restrict__ Wq,   // (64, 512)
    const float* __restrict__ Wk,   // (64, 512)
    float* __restrict__ qbuf,       // (B*N, 64)
    float* __restrict__ kbuf)       // (B*N, 64)
{
    __shared__ float trow[D_DIM];
    const int bn = blockIdx.x;
    const int e  = threadIdx.x;     // 0..63

    // cooperative load of the t row (coalesced)
    #pragma unroll
    for (int idx = 0; idx < D_DIM / 64; ++idx)
        trow[idx * 64 + e] = t[(size_t)bn * D_DIM + idx * 64 + e];
    __syncthreads();

    float aq = 0.f, ak = 0.f;
    const float* wqr = Wq + (size_t)e * D_DIM;
    const float* wkr = Wk + (size_t)e * D_DIM;
    #pragma unroll 8
    for (int d = 0; d < D_DIM; ++d) {
        const float tv = trow[d];   // LDS broadcast (free)
        aq += tv * wqr[d];
        ak += tv * wkr[d];
    }
    qbuf[bn * E_DIM + e] = aq;
    kbuf[bn * E_DIM + e] = ak;
}

// Kernel B: kappa[b,i,j,d] = sum_e q[b,i,e] * k[b,j,e] * Wv[d,e]
// grid = (N/JT, N, B), block = 512 threads, thread = d.
// Per thread: wq[e] = Wv[d,e]*q[b,i,e] in 64 VGPRs; then per j a 64-FMA dot
// with k[b,j,:] whose address is block-uniform -> scalar loads (s_load).
__global__ __launch_bounds__(512) void kappa_kernel(
    const float* __restrict__ qbuf,  // (B*N, 64)
    const float* __restrict__ kbuf,  // (B*N, 64)
    const float* __restrict__ Wv,    // (512, 64)
    float* __restrict__ out,         // (B, N, N, 512)
    int N)
{
    const int d  = threadIdx.x;          // 0..511
    const int jc = blockIdx.x;           // 0..N/JT-1
    const int i  = blockIdx.y;           // 0..N-1
    const int b  = blockIdx.z;           // 0..B-1

    const float* __restrict__ q  = qbuf + ((size_t)(b * N + i)) * E_DIM;   // uniform
    const float* __restrict__ k0 = kbuf + ((size_t)(b * N + jc * JT)) * E_DIM; // uniform

    // wq[e] = Wv[d][e] * q[e]  — Wv row is per-lane contiguous (vectorizes),
    // q is uniform (scalar loads).
    float wq[E_DIM];
    const float* __restrict__ wvr = Wv + (size_t)d * E_DIM;
    #pragma unroll
    for (int e = 0; e < E_DIM; ++e)
        wq[e] = wvr[e] * q[e];

    float* __restrict__ o =
        out + (((size_t)(b * N + i) * N) + (size_t)jc * JT) * D_DIM + d;

    for (int j = 0; j < JT; ++j) {
        const float* __restrict__ kr = k0 + j * E_DIM;  // uniform address
        float acc = 0.f;
        #pragma unroll
        for (int e = 0; e < E_DIM; ++e)
            acc += kr[e] * wq[e];
        o[(size_t)j * D_DIM] = acc;   // lane d contiguous -> coalesced
    }
}

extern "C" void kernel_launch(void* const* d_in, const int* in_sizes, int n_in,
                              void* d_out, int out_size, void* d_ws, size_t ws_size,
                              hipStream_t stream) {
    const float* t  = (const float*)d_in[0];  // (2,512,512)
    const float* Wq = (const float*)d_in[1];  // (64,512)
    const float* Wk = (const float*)d_in[2];  // (64,512)
    const float* Wv = (const float*)d_in[3];  // (512,64)
    float* out = (float*)d_out;

    const int B = 2, N = 512;

    float* qbuf = (float*)d_ws;                    // B*N*64 floats
    float* kbuf = qbuf + (size_t)B * N * E_DIM;    // B*N*64 floats

    qk_proj_kernel<<<dim3(B * N), dim3(64), 0, stream>>>(t, Wq, Wk, qbuf, kbuf);

    dim3 grid(N / JT, N, B);
    kappa_kernel<<<grid, dim3(512), 0, stream>>>(qbuf, kbuf, Wv, out, N);
}

// Round 3
// 249.091 us; speedup vs baseline: 3.9781x; 3.9781x over previous
//
#include <hip/hip_runtime.h>
#include <hip/hip_bf16.h>

#define NB   512   // sequence length N
#define DB   512   // model dim D
#define EB   64    // d_dir

typedef __bf16 bf16x8 __attribute__((ext_vector_type(8)));
typedef float  f32x4  __attribute__((ext_vector_type(4)));

// ---- Kernel A: q = t@Wq^T, k = t@Wk^T, rounded to bf16. 1 wave per (b,n). ----
__global__ __launch_bounds__(64) void qk_proj_bf16(
    const float* __restrict__ t,    // (B*N, 512)
    const float* __restrict__ Wq,   // (64, 512)
    const float* __restrict__ Wk,   // (64, 512)
    __bf16* __restrict__ qb,        // (B*N, 64)
    __bf16* __restrict__ kb)        // (B*N, 64)
{
    __shared__ float trow[DB];
    const int bn = blockIdx.x;
    const int e  = threadIdx.x;     // 0..63
    #pragma unroll
    for (int idx = 0; idx < DB / 64; ++idx)
        trow[idx * 64 + e] = t[(size_t)bn * DB + idx * 64 + e];
    __syncthreads();

    float aq = 0.f, ak = 0.f;
    const float* wqr = Wq + (size_t)e * DB;
    const float* wkr = Wk + (size_t)e * DB;
    #pragma unroll 8
    for (int d = 0; d < DB; ++d) {
        const float tv = trow[d];
        aq += tv * wqr[d];
        ak += tv * wkr[d];
    }
    qb[bn * EB + e] = (__bf16)aq;
    kb[bn * EB + e] = (__bf16)ak;
}

// ---- tiny: Wv fp32 -> bf16 ----
__global__ void wv_to_bf16(const float* __restrict__ Wv, __bf16* __restrict__ wvb, int n)
{
    int i = blockIdx.x * blockDim.x + threadIdx.x;
    if (i < n) wvb[i] = (__bf16)Wv[i];
}

// ---- Kernel B: out[b,i,j,d] = sum_e (k[b,j,e]*q[b,i,e]) * Wv[d,e] via MFMA ----
// grid = (D/128, N/128, B*N); block = 256 (4 waves). Wave w: j-rows [128*jt+32w, +32).
__global__ __launch_bounds__(256) void kappa_mfma(
    const __bf16* __restrict__ qb,   // (B*N, 64)
    const __bf16* __restrict__ kb,   // (B*N, 64)
    const __bf16* __restrict__ wvb,  // (512, 64)  [d][e]
    float* __restrict__ out)         // (B*N, N, 512)
{
    const int dt = blockIdx.x;          // d-tile: 0..3  (128 cols)
    const int jt = blockIdx.y;          // j-tile: 0..3  (128 rows)
    const int bi = blockIdx.z;          // 0..B*N-1  (= b*N + i)
    const int b  = bi >> 9;             // bi / NB   (NB = 512)
    const int w  = threadIdx.x >> 6;    // wave 0..3
    const int l  = threadIdx.x & 63;    // lane
    const int lrow = l & 15;
    const int lgrp = l >> 4;            // k-base = lgrp*8
    const int jb = jt * 128 + w * 32;

    // B-operand fragments: B[e][d] = Wv[d][e]; lane holds col d = dt*128+df*16+lrow,
    // k-range e = ks*32 + lgrp*8 .. +8  -> contiguous 16B in the Wv row. L2-hit.
    bf16x8 bfrag[8][2];
    #pragma unroll
    for (int df = 0; df < 8; ++df) {
        const int d = dt * 128 + df * 16 + lrow;
        #pragma unroll
        for (int ks = 0; ks < 2; ++ks)
            bfrag[df][ks] = *reinterpret_cast<const bf16x8*>(
                wvb + (size_t)d * EB + ks * 32 + lgrp * 8);
    }

    // A-operand fragments: A[j][e] = k[b,j,e] * q[b,i,e] (fold q into k rows).
    bf16x8 afrag[2][2];
    #pragma unroll
    for (int ks = 0; ks < 2; ++ks) {
        const bf16x8 qv = *reinterpret_cast<const bf16x8*>(
            qb + (size_t)bi * EB + ks * 32 + lgrp * 8);
        #pragma unroll
        for (int jf = 0; jf < 2; ++jf) {
            const int j = jb + jf * 16 + lrow;
            // FIX (R2 bug): k row index is b*NB + j, NOT bi*NB + j.
            const bf16x8 kv = *reinterpret_cast<const bf16x8*>(
                kb + ((size_t)b * NB + j) * EB + ks * 32 + lgrp * 8);
            bf16x8 a;
            #pragma unroll
            for (int x = 0; x < 8; ++x)
                a[x] = (__bf16)((float)kv[x] * (float)qv[x]);
            afrag[jf][ks] = a;
        }
    }

    // MFMA accumulate: 2 jf x 8 df x 2 ks = 32 MFMA/wave
    f32x4 acc[2][8];
    #pragma unroll
    for (int jf = 0; jf < 2; ++jf)
        #pragma unroll
        for (int df = 0; df < 8; ++df) {
            acc[jf][df] = (f32x4){0.f, 0.f, 0.f, 0.f};
            acc[jf][df] = __builtin_amdgcn_mfma_f32_16x16x32_bf16(
                afrag[jf][0], bfrag[df][0], acc[jf][df], 0, 0, 0);
            acc[jf][df] = __builtin_amdgcn_mfma_f32_16x16x32_bf16(
                afrag[jf][1], bfrag[df][1], acc[jf][df], 0, 0, 0);
        }

    // Store: C/D layout col = lane&15, row = (lane>>4)*4 + r  [m89-verified]
    #pragma unroll
    for (int jf = 0; jf < 2; ++jf)
        #pragma unroll
        for (int df = 0; df < 8; ++df) {
            const int col = dt * 128 + df * 16 + lrow;
            #pragma unroll
            for (int r = 0; r < 4; ++r) {
                const int row = jb + jf * 16 + lgrp * 4 + r;
                out[((size_t)bi * NB + row) * DB + col] = acc[jf][df][r];
            }
        }
}

extern "C" void kernel_launch(void* const* d_in, const int* in_sizes, int n_in,
                              void* d_out, int out_size, void* d_ws, size_t ws_size,
                              hipStream_t stream) {
    const float* t  = (const float*)d_in[0];  // (2,512,512)
    const float* Wq = (const float*)d_in[1];  // (64,512)
    const float* Wk = (const float*)d_in[2];  // (64,512)
    const float* Wv = (const float*)d_in[3];  // (512,64)
    float* out = (float*)d_out;

    const int B = 2;

    __bf16* qb  = (__bf16*)d_ws;                       // B*N*64
    __bf16* kbf = qb + (size_t)B * NB * EB;            // B*N*64
    __bf16* wvb = kbf + (size_t)B * NB * EB;           // 512*64

    qk_proj_bf16<<<dim3(B * NB), dim3(64), 0, stream>>>(t, Wq, Wk, qb, kbf);
    wv_to_bf16<<<dim3((DB * EB + 255) / 256), dim3(256), 0, stream>>>(Wv, wvb, DB * EB);

    dim3 grid(DB / 128, NB / 128, B * NB);
    kappa_mfma<<<grid, dim3(256), 0, stream>>>(qb, kbf, wvb, out);
}